// Round 1
// 1751.271 us; speedup vs baseline: 1.2628x; 1.2628x over previous
//
#include <hip/hip_runtime.h>

// ---------------------------------------------------------------------------
// InvariantPointAttention, N=1024 C1=384 C2=128 H=12 SQK=SV=16 PQK=4 PV=8
// k1: prep point_weights (softplus) -> f32 ws
// k2: QKV projections (scalar + point w/ rigid transform) -> f32 ws
// k3: attention, ONE q per block (1024 blocks x 512 thr). Full P row (1024x12)
//     lives in LDS (48KB) -> no online-softmax chunking, 7 barriers total.
//     x2d streamed twice (logits pass, res_2d pass), both coalesced/unrolled.
// k4: final (1024x2112)@(2112x384) GEMM -> f32 out
// ---------------------------------------------------------------------------

#define NQ 1024
#define C1D 384
#define C2D 128
#define HH 12
#define FEATD 2112
#define NCHD 384

// ------------------------------- k1: prep ----------------------------------
__global__ void k_prep(const float* __restrict__ raw, float* __restrict__ pwf) {
  int t = threadIdx.x;
  if (t < HH) {
    float x = raw[t];
    pwf[t] = 0.23570226039551584f * log1pf(expf(x)); // sqrt(1/(PQK*9/2))*softplus
  }
}

// ---------------------------- k2: projections ------------------------------
// grid (128, 3), block 256. Each block: 8 rows of inputs_1d, 256 "units".
__global__ __launch_bounds__(256) void k_proj(
    const float* __restrict__ x1d, const float* __restrict__ rot, const float* __restrict__ trans,
    const float* __restrict__ wq_p, const float* __restrict__ bq_p,
    const float* __restrict__ wk_p, const float* __restrict__ bk_p,
    const float* __restrict__ wv_p, const float* __restrict__ bv_p,
    const float* __restrict__ wq_s, const float* __restrict__ wk_s, const float* __restrict__ wv_s,
    float* __restrict__ qs, float* __restrict__ ks_, float* __restrict__ vs,
    float* __restrict__ qp, float* __restrict__ kp, float* __restrict__ vp) {
  __shared__ float xs[8 * C1D];
  const int n0 = blockIdx.x * 8;
  const int t = threadIdx.x;
  for (int i = t; i < 8 * C1D; i += 256) xs[i] = x1d[(size_t)n0 * C1D + i];
  __syncthreads();
  const int u = blockIdx.y * 256 + t;
  if (u < 576) {
    const float* W; float* dst; float scale = 1.0f; int col;
    if (u < 192)      { W = wq_s; dst = qs;  col = u;       scale = 0.25f; }
    else if (u < 384) { W = wk_s; dst = ks_; col = u - 192; }
    else              { W = wv_s; dst = vs;  col = u - 384; }
    float acc[8];
#pragma unroll
    for (int r = 0; r < 8; ++r) acc[r] = 0.f;
    for (int c = 0; c < C1D; ++c) {
      float w = W[c * 192 + col];
#pragma unroll
      for (int r = 0; r < 8; ++r) acc[r] += xs[r * C1D + c] * w;
    }
    for (int r = 0; r < 8; ++r) dst[(size_t)(n0 + r) * 192 + col] = acc[r] * scale;
  } else {
    const float* W; const float* B; float* dst; int h, p, np_;
    if (u < 624)      { W = wq_p; B = bq_p; dst = qp; int v = u - 576; h = v / 4; p = v % 4; np_ = 4; }
    else if (u < 672) { W = wk_p; B = bk_p; dst = kp; int v = u - 624; h = v / 4; p = v % 4; np_ = 4; }
    else              { W = wv_p; B = bv_p; dst = vp; int v = u - 672; h = v / 8; p = v % 8; np_ = 8; }
    const int str = 36 * np_;
    const int c0 = h * 3 * np_ + p;
    float a0[8], a1[8], a2[8];
#pragma unroll
    for (int r = 0; r < 8; ++r) { a0[r] = 0.f; a1[r] = 0.f; a2[r] = 0.f; }
    for (int c = 0; c < C1D; ++c) {
      float w0 = W[c * str + c0];
      float w1 = W[c * str + c0 + np_];
      float w2 = W[c * str + c0 + 2 * np_];
#pragma unroll
      for (int r = 0; r < 8; ++r) {
        float x = xs[r * C1D + c];
        a0[r] += x * w0; a1[r] += x * w1; a2[r] += x * w2;
      }
    }
    const float b0 = B[c0], b1 = B[c0 + np_], b2 = B[c0 + 2 * np_];
    for (int r = 0; r < 8; ++r) {
      const int n = n0 + r;
      float l0 = a0[r] + b0, l1 = a1[r] + b1, l2 = a2[r] + b2;
      float R0 = rot[n * 9 + 0], R1 = rot[n * 9 + 1], R2 = rot[n * 9 + 2];
      float R3 = rot[n * 9 + 3], R4 = rot[n * 9 + 4], R5 = rot[n * 9 + 5];
      float R6 = rot[n * 9 + 6], R7 = rot[n * 9 + 7], R8 = rot[n * 9 + 8];
      float T0 = trans[n * 3 + 0], T1 = trans[n * 3 + 1], T2 = trans[n * 3 + 2];
      float g0 = R0 * l0 + R1 * l1 + R2 * l2 + T0;
      float g1 = R3 * l0 + R4 * l1 + R5 * l2 + T1;
      float g2 = R6 * l0 + R7 * l1 + R8 * l2 + T2;
      size_t o = (size_t)n * str + (size_t)(h * np_ + p) * 3;
      dst[o] = g0; dst[o + 1] = g1; dst[o + 2] = g2;
    }
  }
}

// --------------------------- k3: attention ---------------------------------
// ONE q per block. grid 1024, block 512 (8 waves). 2 blocks/CU (VGPR<=128,
// LDS ~52KB). Full probs matrix PT[12][1024] in LDS -> single softmax, no
// chunk barriers. x2d read twice: P1 (per-lane row, L1-tiled) + P3 (coalesced).
__global__ __launch_bounds__(512, 4) void k_attn(
    const float* __restrict__ x2d, const float* __restrict__ mask,
    const float* __restrict__ rot, const float* __restrict__ trans,
    const float* __restrict__ w2d, const float* __restrict__ b2d, const float* __restrict__ pwf,
    const float* __restrict__ qs, const float* __restrict__ ks_, const float* __restrict__ vs,
    const float* __restrict__ qp, const float* __restrict__ kp, const float* __restrict__ vp,
    float* __restrict__ feat) {
  __shared__ __attribute__((aligned(16))) float PT[HH * NQ];  // 48KB, [h][k]
  __shared__ __attribute__((aligned(16))) float qsl[192];
  __shared__ __attribute__((aligned(16))) float qpl[144];
  __shared__ float wred[8 * 12];
  __shared__ float mh[12], sinv[12];
  __shared__ float Gl[288];

  const int t = threadIdx.x;
  const int q = blockIdx.x;

  if (t < 192) qsl[t] = qs[(size_t)q * 192 + t];
  if (t >= 256 && t < 400) qpl[t - 256] = qp[(size_t)q * 144 + (t - 256)];

  float bh[12], pw[12];
#pragma unroll
  for (int h = 0; h < 12; ++h) { bh[h] = b2d[h]; pw[h] = pwf[h]; }
  const float mq = mask[q];
  __syncthreads();

  // ---- P1: logits for k = t and t+512, all 12 heads -> PT ----
  float pmax[12];
#pragma unroll
  for (int h = 0; h < 12; ++h) pmax[h] = -3.0e38f;

  for (int j = 0; j < 2; ++j) {
    const int k = t + j * 512;
    float acc[12];
#pragma unroll
    for (int h = 0; h < 12; ++h) acc[h] = bh[h];
    // 2d term: x2d[q,k,:] @ w2d (w2d wave-uniform -> scalar loads)
    const float4* xr4 = (const float4*)(x2d + ((size_t)q * NQ + (size_t)k) * C2D);
#pragma unroll 4
    for (int g = 0; g < 32; ++g) {
      float4 xv = xr4[g];
      const float* wr = w2d + (g * 4) * 12;
#pragma unroll
      for (int h = 0; h < 12; ++h)
        acc[h] += xv.x * wr[h] + xv.y * wr[12 + h] + xv.z * wr[24 + h] + xv.w * wr[36 + h];
    }
    // scalar qk (qs row broadcast from LDS)
    const float4* kr4 = (const float4*)(ks_ + (size_t)k * 192);
    const float4* qr4 = (const float4*)qsl;
#pragma unroll
    for (int h = 0; h < 12; ++h) {
      float d = 0.f;
#pragma unroll
      for (int jj = 0; jj < 4; ++jj) {
        float4 a = qr4[h * 4 + jj]; float4 b = kr4[h * 4 + jj];
        d += a.x * b.x + a.y * b.y + a.z * b.z + a.w * b.w;
      }
      acc[h] += d;
    }
    // point term
    const float4* kp4 = (const float4*)(kp + (size_t)k * 144);
#pragma unroll
    for (int h = 0; h < 12; ++h) {
      float4 u0 = kp4[h * 3], u1 = kp4[h * 3 + 1], u2 = kp4[h * 3 + 2];
      const float* qb = &qpl[h * 12];
      float dx, dy, dz, d2 = 0.f;
      dx = qb[0] - u0.x; dy = qb[1]  - u0.y; dz = qb[2]  - u0.z; d2 += dx*dx + dy*dy + dz*dz;
      dx = qb[3] - u0.w; dy = qb[4]  - u1.x; dz = qb[5]  - u1.y; d2 += dx*dx + dy*dy + dz*dz;
      dx = qb[6] - u1.z; dy = qb[7]  - u1.w; dz = qb[8]  - u2.x; d2 += dx*dx + dy*dy + dz*dz;
      dx = qb[9] - u2.y; dy = qb[10] - u2.z; dz = qb[11] - u2.w; d2 += dx*dx + dy*dy + dz*dz;
      acc[h] -= 0.5f * pw[h] * d2;
    }
    const float mk = mask[k];
    const float mt = -100000.0f * (1.0f - mq * mk);
#pragma unroll
    for (int h = 0; h < 12; ++h) {
      float v = (acc[h] + mt) * 0.5773502691896258f;
      PT[h * NQ + k] = v;
      pmax[h] = fmaxf(pmax[h], v);
    }
  }

  // ---- P2: block max-reduce, exp in LDS, sum-reduce -> sinv ----
#pragma unroll
  for (int off = 32; off > 0; off >>= 1)
#pragma unroll
    for (int h = 0; h < 12; ++h) pmax[h] = fmaxf(pmax[h], __shfl_xor(pmax[h], off));
  const int wid = t >> 6, lane = t & 63;
  if (lane == 0)
#pragma unroll
    for (int h = 0; h < 12; ++h) wred[wid * 12 + h] = pmax[h];
  __syncthreads();
  if (t < 12) {
    float m = wred[t];
#pragma unroll
    for (int w = 1; w < 8; ++w) m = fmaxf(m, wred[w * 12 + t]);
    mh[t] = m;
  }
  __syncthreads();
  float psum[12];
#pragma unroll
  for (int h = 0; h < 12; ++h) psum[h] = 0.f;
  for (int j = 0; j < 2; ++j) {
    const int k = t + j * 512;
#pragma unroll
    for (int h = 0; h < 12; ++h) {
      float v = expf(PT[h * NQ + k] - mh[h]);
      PT[h * NQ + k] = v;
      psum[h] += v;
    }
  }
#pragma unroll
  for (int off = 32; off > 0; off >>= 1)
#pragma unroll
    for (int h = 0; h < 12; ++h) psum[h] += __shfl_xor(psum[h], off);
  if (lane == 0)
#pragma unroll
    for (int h = 0; h < 12; ++h) wred[wid * 12 + h] = psum[h];
  __syncthreads();
  if (t < 12) {
    float s = wred[t];
#pragma unroll
    for (int w = 1; w < 8; ++w) s += wred[w * 12 + t];
    sinv[t] = 1.0f / s;
  }
  __syncthreads();

  // ---- P3: res_2d. thread owns channel c for 3 heads; x2d coalesced,
  //          P broadcast float4 from LDS; 8-deep unrolled loads ----
  {
    const int c = t & 127;
    const int h0 = (t >> 7) * 3;
    float a0 = 0.f, a1 = 0.f, a2 = 0.f;
    const float* xc = x2d + (size_t)q * NQ * C2D + c;
    const float* Pa = &PT[(h0 + 0) * NQ];
    const float* Pb = &PT[(h0 + 1) * NQ];
    const float* Pc = &PT[(h0 + 2) * NQ];
    for (int k = 0; k < NQ; k += 8) {
      float x0 = xc[(size_t)(k + 0) * C2D], x1 = xc[(size_t)(k + 1) * C2D];
      float x2 = xc[(size_t)(k + 2) * C2D], x3 = xc[(size_t)(k + 3) * C2D];
      float x4 = xc[(size_t)(k + 4) * C2D], x5 = xc[(size_t)(k + 5) * C2D];
      float x6 = xc[(size_t)(k + 6) * C2D], x7 = xc[(size_t)(k + 7) * C2D];
      float4 pa0 = *(const float4*)&Pa[k], pa1 = *(const float4*)&Pa[k + 4];
      float4 pb0 = *(const float4*)&Pb[k], pb1 = *(const float4*)&Pb[k + 4];
      float4 pc0 = *(const float4*)&Pc[k], pc1 = *(const float4*)&Pc[k + 4];
      a0 += pa0.x * x0 + pa0.y * x1 + pa0.z * x2 + pa0.w * x3
          + pa1.x * x4 + pa1.y * x5 + pa1.z * x6 + pa1.w * x7;
      a1 += pb0.x * x0 + pb0.y * x1 + pb0.z * x2 + pb0.w * x3
          + pb1.x * x4 + pb1.y * x5 + pb1.z * x6 + pb1.w * x7;
      a2 += pc0.x * x0 + pc0.y * x1 + pc0.z * x2 + pc0.w * x3
          + pc1.x * x4 + pc1.y * x5 + pc1.z * x6 + pc1.w * x7;
    }
    float* fb = feat + (size_t)q * FEATD + 576 + c;
    fb[(size_t)(h0 + 0) * 128] = a0 * sinv[h0 + 0];
    fb[(size_t)(h0 + 1) * 128] = a1 * sinv[h0 + 1];
    fb[(size_t)(h0 + 2) * 128] = a2 * sinv[h0 + 2];
  }

  // ---- P4: v_scalar / v_point. 480 threads, one output each; per-k the
  //          block reads exactly vs-row U vp-row (coalesced, L2-resident) ----
  if (t < 480) {
    const int h = t / 40, r = t % 40;
    const float* src; int str, off;
    if (r < 16) { src = vs; str = 192; off = h * 16 + r; }
    else        { src = vp; str = 288; off = h * 24 + (r - 16); }
    const float* Ph = &PT[h * NQ];
    float acc = 0.f;
    for (int k = 0; k < NQ; k += 4) {
      acc += Ph[k]     * src[(size_t)(k)     * str + off]
           + Ph[k + 1] * src[(size_t)(k + 1) * str + off]
           + Ph[k + 2] * src[(size_t)(k + 2) * str + off]
           + Ph[k + 3] * src[(size_t)(k + 3) * str + off];
    }
    acc *= sinv[h];
    if (r < 16) feat[(size_t)q * FEATD + h * 16 + r] = acc;
    else Gl[h * 24 + (r - 16)] = acc;
  }
  __syncthreads();

  // ---- P5: rigid inverse + norms ----
  if (t < 96) {
    const int u = t;
    float R[9], T[3];
#pragma unroll
    for (int i = 0; i < 9; ++i) R[i] = rot[q * 9 + i];
#pragma unroll
    for (int i = 0; i < 3; ++i) T[i] = trans[q * 3 + i];
    float g0 = Gl[u * 3 + 0] - T[0];
    float g1 = Gl[u * 3 + 1] - T[1];
    float g2 = Gl[u * 3 + 2] - T[2];
    float l0 = R[0] * g0 + R[3] * g1 + R[6] * g2;  // R^T (g - t)
    float l1 = R[1] * g0 + R[4] * g1 + R[7] * g2;
    float l2 = R[2] * g0 + R[5] * g1 + R[8] * g2;
    float n2 = l0 * l0 + l1 * l1 + l2 * l2;
    float* fb = feat + (size_t)q * FEATD;
    fb[192 + u] = l0; fb[288 + u] = l1; fb[384 + u] = l2;
    fb[480 + u] = sqrtf(fmaxf(n2, 1e-16f));
  }
}

// ----------------------------- k4: output GEMM -----------------------------
// grid (32, 12), block 256. 32x32 tile, 2x2 per thread. K = 2112 = 66*32.
__global__ __launch_bounds__(256) void k_out(
    const float* __restrict__ feat, const float* __restrict__ wout,
    const float* __restrict__ bout, float* __restrict__ out) {
  __shared__ float A[32][33];
  __shared__ float B[32][33];
  const int t = threadIdx.x;
  const int row0 = blockIdx.x * 32, col0 = blockIdx.y * 32;
  const int r0 = t >> 4, c0 = t & 15;
  float acc[2][2] = {{0.f, 0.f}, {0.f, 0.f}};
  for (int k0 = 0; k0 < FEATD; k0 += 32) {
    for (int idx = t; idx < 1024; idx += 256) {
      int i = idx >> 5, j = idx & 31;
      A[i][j] = feat[(size_t)(row0 + i) * FEATD + k0 + j];
      B[i][j] = wout[(size_t)(k0 + i) * NCHD + col0 + j];
    }
    __syncthreads();
#pragma unroll 8
    for (int kk = 0; kk < 32; ++kk) {
      float a0 = A[r0][kk], a1 = A[r0 + 16][kk];
      float b0 = B[kk][c0], b1 = B[kk][c0 + 16];
      acc[0][0] += a0 * b0; acc[0][1] += a0 * b1;
      acc[1][0] += a1 * b0; acc[1][1] += a1 * b1;
    }
    __syncthreads();
  }
#pragma unroll
  for (int r = 0; r < 2; ++r)
#pragma unroll
    for (int c = 0; c < 2; ++c) {
      int rr = row0 + r0 + r * 16, cc = col0 + c0 + c * 16;
      out[(size_t)rr * NCHD + cc] = acc[r][c] + bout[cc];
    }
}

// ------------------------------ launcher -----------------------------------
extern "C" void kernel_launch(void* const* d_in, const int* in_sizes, int n_in,
                              void* d_out, int out_size, void* d_ws, size_t ws_size,
                              hipStream_t stream) {
  const float* x1d   = (const float*)d_in[0];
  const float* x2d   = (const float*)d_in[1];
  const float* mask  = (const float*)d_in[2];
  const float* rot   = (const float*)d_in[3];
  const float* trans = (const float*)d_in[4];
  const float* raw   = (const float*)d_in[5];
  const float* wq_p  = (const float*)d_in[6];
  const float* bq_p  = (const float*)d_in[7];
  const float* wk_p  = (const float*)d_in[8];
  const float* bk_p  = (const float*)d_in[9];
  const float* wv_p  = (const float*)d_in[10];
  const float* bv_p  = (const float*)d_in[11];
  const float* wq_s  = (const float*)d_in[12];
  const float* wk_s  = (const float*)d_in[13];
  const float* wv_s  = (const float*)d_in[14];
  const float* w2d   = (const float*)d_in[15];
  const float* b2d   = (const float*)d_in[16];
  const float* wout  = (const float*)d_in[17];
  const float* bout  = (const float*)d_in[18];

  float* ws   = (float*)d_ws;
  float* qs   = ws;                  // 1024*192
  float* ks_  = qs  + 196608;
  float* vs   = ks_ + 196608;
  float* qp   = vs  + 196608;        // 1024*144
  float* kp   = qp  + 147456;
  float* vp   = kp  + 147456;        // 1024*288
  float* feat = vp  + 294912;        // 1024*2112
  float* pwf  = feat + 2162688;      // 12

  k_prep<<<dim3(1), 64, 0, stream>>>(raw, pwf);
  k_proj<<<dim3(128, 3), 256, 0, stream>>>(x1d, rot, trans, wq_p, bq_p, wk_p, bk_p,
                                           wv_p, bv_p, wq_s, wk_s, wv_s,
                                           qs, ks_, vs, qp, kp, vp);
  k_attn<<<dim3(1024), 512, 0, stream>>>(x2d, mask, rot, trans, w2d, b2d, pwf,
                                         qs, ks_, vs, qp, kp, vp, feat);
  k_out<<<dim3(32, 12), 256, 0, stream>>>(feat, wout, bout, (float*)d_out);
}